// Round 15
// baseline (582.452 us; speedup 1.0000x reference)
//
#include <hip/hip_runtime.h>
#include <math.h>

#define NN 20000
#define NE 200000
#define NT 40000
#define HP 136  // padded LDS row stride (fp16) for link H/W tiles

typedef _Float16 f16;
typedef __attribute__((ext_vector_type(8))) _Float16 f16x8;
typedef __attribute__((ext_vector_type(4))) float f32x4;
typedef __attribute__((ext_vector_type(2))) _Float16 h2;

// ---------------- edge weight MLP (+ CSR count fused) ----------------
__global__ void k_edge_mlp(const float* __restrict__ ea,
                           const float* __restrict__ w1, const float* __restrict__ b1,
                           const float* __restrict__ w2, const float* __restrict__ b2,
                           const float* __restrict__ w3, const float* __restrict__ b3,
                           const int* __restrict__ col,
                           float* __restrict__ out, int* __restrict__ cnt) {
  int e = blockIdx.x * 256 + threadIdx.x;
  if (e >= NE) return;
  atomicAdd(&cnt[col[e]], 1);
  float a[7];
#pragma unroll
  for (int i = 0; i < 7; i++) a[i] = ea[e * 7 + i];
  float t1[28];
#pragma unroll
  for (int j = 0; j < 28; j++) {
    float s = b1[j];
#pragma unroll
    for (int k = 0; k < 7; k++) s = fmaf(a[k], w1[k * 28 + j], s);
    t1[j] = fmaxf(s, 0.f);
  }
  float t2[28];
  for (int j = 0; j < 28; j++) {
    float s = b2[j];
    for (int k = 0; k < 28; k++) s = fmaf(t1[k], w2[k * 28 + j], s);
    t2[j] = fmaxf(s, 0.f);
  }
  float s = b3[0];
  for (int k = 0; k < 28; k++) s = fmaf(t2[k], w3[k], s);
  out[e] = 1.f / (1.f + expf(-s));
}

// ---------------- CSR scan: rowptr + cursor in one pass ----------------
__global__ void k_scan(int* __restrict__ cnt, int* __restrict__ rowptr) {
  __shared__ int sums[256];
  __shared__ int offs[256];
  int t = threadIdx.x;
  const int CH = (NN + 255) / 256;
  int base = t * CH;
  int s = 0;
  for (int i = 0; i < CH; i++) { int idx = base + i; if (idx < NN) s += cnt[idx]; }
  sums[t] = s;
  __syncthreads();
  if (t == 0) {
    int acc = 0;
    for (int i = 0; i < 256; i++) { offs[i] = acc; acc += sums[i]; }
    rowptr[NN] = acc;
  }
  __syncthreads();
  int acc = offs[t];
  for (int i = 0; i < CH; i++) {
    int idx = base + i;
    if (idx < NN) {
      int cv = cnt[idx];
      rowptr[idx] = acc;
      cnt[idx] = acc;  // becomes the fill cursor
      acc += cv;
    }
  }
}

__global__ void k_fill_csr(const int* __restrict__ col, int* __restrict__ cursor,
                           int* __restrict__ eid) {
  int e = blockIdx.x * 256 + threadIdx.x;
  if (e >= NE) return;
  int pos = atomicAdd(&cursor[col[e]], 1);
  eid[pos] = e;
}

// degrees from CSR (no float atomics). 8 nodes x 8 relations per 64-thread block.
__global__ __launch_bounds__(64) void k_deg_csr(const int* __restrict__ rowptr,
                                                const int* __restrict__ eid,
                                                const float* __restrict__ ea,
                                                const float* __restrict__ ewb,
                                                float* __restrict__ dis) {
  int t = threadIdx.x;
  int n = blockIdx.x * 8 + (t >> 3);
  int i = t & 7;
  if (n >= NN) return;
  float deg = 1.f;  // self-loop weight
  int s = rowptr[n], e2 = rowptr[n + 1];
  for (int p = s; p < e2; p++) {
    int e = eid[p];
    deg += (i < 7) ? ea[e * 7 + i] : ewb[e];
  }
  dis[i * NN + n] = rsqrtf(deg);  // deg >= 1 always
}

// norms stored fp16 (<=1, positive; 2^-11 relative — same class as the other
// measured-free quantizations). Halves norm traffic in every agg kernel.
__global__ void k_csr_norms(const int* __restrict__ eid, const int* __restrict__ row,
                            const int* __restrict__ col, const float* __restrict__ ea,
                            const float* __restrict__ ew, const float* __restrict__ dis,
                            int* __restrict__ csr_src, f16* __restrict__ csr_norm) {
  int p = blockIdx.x * 256 + threadIdx.x;
  if (p >= NE) return;
  int e = eid[p];
  int r = row[e], c = col[e];
  csr_src[p] = r;
#pragma unroll
  for (int i = 0; i < 7; i++)
    csr_norm[(size_t)i * NE + p] = (f16)(dis[i * NN + r] * ea[e * 7 + i] * dis[i * NN + c]);
  csr_norm[(size_t)7 * NE + p] = (f16)(dis[7 * NN + r] * ew[e] * dis[7 * NN + c]);
}

// ---------------- single-launch weight prep (all 5 mats) + cursor zero ----------------
__global__ void k_wprep_all(const float* __restrict__ W1, const float* __restrict__ W2,
                            const float* __restrict__ W3, const float* __restrict__ lw0,
                            const float* __restrict__ lwh,
                            f16* __restrict__ w1t, f16* __restrict__ w2t,
                            f16* __restrict__ w3t, f16* __restrict__ lw0t,
                            f16* __restrict__ lwht, int* __restrict__ cursor) {
  int b = blockIdx.x, t = threadIdx.x;
  const float* W;
  f16* D;
  int K, g, tile;
  size_t matOff;
  if (b < 448) {            // W1: K=896, 1 mat
    W = W1; D = w1t; K = 896; g = 0; tile = b; matOff = 0;
  } else if (b < 896) {     // W2: K=128, 7 mats
    int l = b - 448; W = W2; D = w2t; K = 128; g = l >> 6; tile = l & 63;
    matOff = 16384;
  } else if (b < 4032) {    // W3: K=896, 7 mats
    int l = b - 896; W = W3; D = w3t; K = 896; g = l / 448; tile = l % 448;
    matOff = 114688;
  } else if (b < 4928) {    // lw0: K=896, 2 mats (U rows 0..895, V rows 896..1791)
    int l = b - 4032; W = lw0; D = lw0t; K = 896; g = l / 448; tile = l % 448;
    matOff = 114688;
  } else if (b < 5120) {    // lwh: K=128, 3 mats
    int l = b - 4928; W = lwh; D = lwht; K = 128; g = l >> 6; tile = l & 63;
    matOff = 16384;
  } else {                  // zero the CSR cursor
    int idx = (b - 5120) * 256 + t;
    if (idx < NN) cursor[idx] = 0;
    return;
  }
  int idx = tile * 256 + t;
  int k = idx >> 7, n = idx & 127;
  float v = W[(size_t)g * matOff + (size_t)k * 128 + n];
  D[(size_t)g * 128 * K + (size_t)n * K + k] = (f16)v;
}

// ---------------- fp16 MFMA GEMM (1-term) ----------------
template <int OUTM, bool RELU, bool BIAS, bool GROUP_A, bool SWIZZLE>
__global__ __launch_bounds__(256) void k_mgemm(
    const f16* __restrict__ A, const f16* __restrict__ BT,
    const float* __restrict__ bias,
    float* __restrict__ Cf, f16* __restrict__ Ch,
    int ldA, int M, int K, int NG, int GXp) {
  int rowT, g;
  if (SWIZZLE) {
    int b = blockIdx.x;
    int xcd = b & 7, s = b >> 3;
    g = s % NG;
    int lr = s / NG;
    rowT = lr * 8 + xcd;
    if (rowT >= GXp) return;  // uniform early-out (padded grid)
  } else {
    rowT = blockIdx.x;
    g = blockIdx.y;
  }
  __shared__ f16 smem[8192];  // 2 tiles [128 rows][32 k] fp16: A, B
  const int tid = threadIdx.x;
  const int w = tid >> 6, lane = tid & 63;
  const int quad = lane >> 4, lc = lane & 15;
  const int wr = w >> 1, wc = w & 1;
  const int bm = rowT * 128;
  const int ldC = NG * 128;
  const int cb = g * 128;
  const int aoff = GROUP_A ? g * K : 0;
  const f16* Bg = BT + (size_t)g * 128 * K;
  const int srow = lane >> 2, skoff = (lane & 3) * 8;

  f32x4 acc[4][4] = {};

  for (int k0 = 0; k0 < K; k0 += 32) {
#pragma unroll
    for (int l = 0; l < 4; l++) {
      int c = w + l * 4;
      int t = c >> 3, r16 = c & 7;
      int rowi = r16 * 16 + srow;
      f16* ldst = smem + t * 4096 + r16 * 512;  // +lane*16B implicit
      const f16* src;
      if (t == 0) {
        int gm = bm + rowi;
        if (gm > M - 1) gm = M - 1;  // clamp; guarded at store
        src = A + (size_t)gm * ldA + aoff + k0 + skoff;
      } else {
        src = Bg + (size_t)rowi * K + k0 + skoff;
      }
      __builtin_amdgcn_global_load_lds(
          (const __attribute__((address_space(1))) void*)src,
          (__attribute__((address_space(3))) void*)ldst, 16, 0, 0);
    }
    __syncthreads();
    f16x8 bf[4];
#pragma unroll
    for (int nt = 0; nt < 4; nt++) {
      int r = wc * 64 + nt * 16 + lc;
      bf[nt] = *(const f16x8*)(smem + 4096 + r * 32 + quad * 8);
    }
#pragma unroll
    for (int mt = 0; mt < 4; mt++) {
      int r = wr * 64 + mt * 16 + lc;
      f16x8 ah = *(const f16x8*)(smem + r * 32 + quad * 8);
#pragma unroll
      for (int nt = 0; nt < 4; nt++) {
        acc[mt][nt] = __builtin_amdgcn_mfma_f32_16x16x32_f16(ah, bf[nt], acc[mt][nt], 0, 0, 0);
      }
    }
    __syncthreads();
  }

  float bv[4];
  if (BIAS) {
#pragma unroll
    for (int nt = 0; nt < 4; nt++) bv[nt] = bias[cb + wc * 64 + nt * 16 + lc];
  }
#pragma unroll
  for (int mt = 0; mt < 4; mt++) {
#pragma unroll
    for (int r = 0; r < 4; r++) {
      int gm = bm + wr * 64 + mt * 16 + quad * 4 + r;
      if (gm >= M) continue;
#pragma unroll
      for (int nt = 0; nt < 4; nt++) {
        float v = acc[mt][nt][r];
        if (BIAS) v += bv[nt];
        if (RELU) v = fmaxf(v, 0.f);
        size_t idx = (size_t)gm * ldC + cb + wc * 64 + nt * 16 + lc;
        if (OUTM == 1) Ch[idx] = (f16)v;
        else Cf[idx] = v;
      }
    }
  }
}

// ---------------- layer-3 aggregation: R11-proven node-per-block, unroll-8 ----
__global__ __launch_bounds__(448) void k_agg7(const f16* __restrict__ hW,
                                              const f16* __restrict__ csr_norm,
                                              const float* __restrict__ dis,
                                              const int* __restrict__ rowptr,
                                              const int* __restrict__ csr_src,
                                              const float* __restrict__ bias,
                                              f16* __restrict__ outq) {
  int n = blockIdx.x;
  int f2 = threadIdx.x;   // handles h2 col f2 (cols 2*f2, 2*f2+1)
  int i = f2 >> 6;        // wave-uniform relation
  const h2* hw2 = (const h2*)hW;
  const f16* nrm = csr_norm + (size_t)i * NE;
  float d = dis[i * NN + n];
  h2 sv = hw2[(size_t)n * 448 + f2];
  float ax = d * d * (float)sv.x, ay = d * d * (float)sv.y;
  int s = rowptr[n], e = rowptr[n + 1];
  int p = s;
  for (; p + 8 <= e; p += 8) {
    int si[8];
    float nn_[8];
    h2 vv[8];
#pragma unroll
    for (int u = 0; u < 8; u++) { si[u] = csr_src[p + u]; nn_[u] = (float)nrm[p + u]; }
#pragma unroll
    for (int u = 0; u < 8; u++) vv[u] = hw2[(size_t)si[u] * 448 + f2];
#pragma unroll
    for (int u = 0; u < 8; u++) {
      ax = fmaf(nn_[u], (float)vv[u].x, ax);
      ay = fmaf(nn_[u], (float)vv[u].y, ay);
    }
  }
  for (; p + 4 <= e; p += 4) {
    int s0 = csr_src[p], s1 = csr_src[p + 1], s2 = csr_src[p + 2], s3 = csr_src[p + 3];
    float n0 = (float)nrm[p], n1 = (float)nrm[p + 1];
    float n2 = (float)nrm[p + 2], n3 = (float)nrm[p + 3];
    h2 v0 = hw2[(size_t)s0 * 448 + f2];
    h2 v1 = hw2[(size_t)s1 * 448 + f2];
    h2 v2 = hw2[(size_t)s2 * 448 + f2];
    h2 v3 = hw2[(size_t)s3 * 448 + f2];
    ax = fmaf(n0, (float)v0.x, ax); ay = fmaf(n0, (float)v0.y, ay);
    ax = fmaf(n1, (float)v1.x, ax); ay = fmaf(n1, (float)v1.y, ay);
    ax = fmaf(n2, (float)v2.x, ax); ay = fmaf(n2, (float)v2.y, ay);
    ax = fmaf(n3, (float)v3.x, ax); ay = fmaf(n3, (float)v3.y, ay);
  }
  for (; p < e; p++) {
    int s0 = csr_src[p];
    float n0 = (float)nrm[p];
    h2 v0 = hw2[(size_t)s0 * 448 + f2];
    ax = fmaf(n0, (float)v0.x, ax); ay = fmaf(n0, (float)v0.y, ay);
  }
  h2 o;
  o.x = (f16)fmaxf(ax + bias[2 * f2], 0.f);
  o.y = (f16)fmaxf(ay + bias[2 * f2 + 1], 0.f);
  ((h2*)outq)[(size_t)n * 448 + f2] = o;
}

// ---------------- layer-1 aggregation: fp16 gather, fp16 out, unroll-8 ----------------
__global__ __launch_bounds__(256) void k_agg1(const f16* __restrict__ hW,
                                              const f16* __restrict__ nrm,
                                              const float* __restrict__ dis_i,
                                              const int* __restrict__ rowptr,
                                              const int* __restrict__ csr_src,
                                              const float* __restrict__ bias,
                                              f16* __restrict__ x2h) {
  int t = threadIdx.x;
  int n = blockIdx.x * 4 + (t >> 6);
  int f2 = t & 63;
  if (n >= NN) return;
  const h2* hw2 = (const h2*)hW;
  float d = dis_i[n];
  h2 sv = hw2[(size_t)n * 64 + f2];
  float ax = d * d * (float)sv.x, ay = d * d * (float)sv.y;
  int s = rowptr[n], e = rowptr[n + 1];
  int p = s;
  for (; p + 8 <= e; p += 8) {
    int si[8];
    float nn_[8];
    h2 vv[8];
#pragma unroll
    for (int u = 0; u < 8; u++) { si[u] = csr_src[p + u]; nn_[u] = (float)nrm[p + u]; }
#pragma unroll
    for (int u = 0; u < 8; u++) vv[u] = hw2[(size_t)si[u] * 64 + f2];
#pragma unroll
    for (int u = 0; u < 8; u++) {
      ax = fmaf(nn_[u], (float)vv[u].x, ax);
      ay = fmaf(nn_[u], (float)vv[u].y, ay);
    }
  }
  for (; p < e; p++) {
    int s0 = csr_src[p];
    float n0 = (float)nrm[p];
    h2 v0 = hw2[(size_t)s0 * 64 + f2];
    ax = fmaf(n0, (float)v0.x, ax); ay = fmaf(n0, (float)v0.y, ay);
  }
  h2 o;
  o.x = (f16)fmaxf(ax + bias[2 * f2], 0.f);
  o.y = (f16)fmaxf(ay + bias[2 * f2 + 1], 0.f);
  ((h2*)x2h)[(size_t)n * 64 + f2] = o;
}

// ---------------- layer-2 aggregate-first: fp16 gather of x2, 7 norms, unroll-8 ----
__global__ __launch_bounds__(256) void k_agg2(const f16* __restrict__ x2h,
                                              const f16* __restrict__ csr_norm,
                                              const float* __restrict__ dis,
                                              const int* __restrict__ rowptr,
                                              const int* __restrict__ csr_src,
                                              f16* __restrict__ oq) {
  int t = threadIdx.x;
  int n = blockIdx.x * 4 + (t >> 6);
  int f2 = t & 63;
  if (n >= NN) return;
  const h2* x2 = (const h2*)x2h;
  h2 svh = x2[(size_t)n * 64 + f2];
  float svx = (float)svh.x, svy = (float)svh.y;
  float ax[7], ay[7];
#pragma unroll
  for (int i = 0; i < 7; i++) {
    float d = dis[i * NN + n];
    ax[i] = d * d * svx;
    ay[i] = d * d * svy;
  }
  int s = rowptr[n], e = rowptr[n + 1];
  int p = s;
  for (; p + 8 <= e; p += 8) {
    int si[8];
    h2 vv[8];
#pragma unroll
    for (int u = 0; u < 8; u++) si[u] = csr_src[p + u];
#pragma unroll
    for (int u = 0; u < 8; u++) vv[u] = x2[(size_t)si[u] * 64 + f2];
#pragma unroll
    for (int i = 0; i < 7; i++) {
#pragma unroll
      for (int u = 0; u < 8; u++) {
        float nw = (float)csr_norm[(size_t)i * NE + p + u];
        ax[i] = fmaf(nw, (float)vv[u].x, ax[i]);
        ay[i] = fmaf(nw, (float)vv[u].y, ay[i]);
      }
    }
  }
  for (; p < e; p++) {
    int s0 = csr_src[p];
    h2 v0 = x2[(size_t)s0 * 64 + f2];
#pragma unroll
    for (int i = 0; i < 7; i++) {
      float nw = (float)csr_norm[(size_t)i * NE + p];
      ax[i] = fmaf(nw, (float)v0.x, ax[i]);
      ay[i] = fmaf(nw, (float)v0.y, ay[i]);
    }
  }
#pragma unroll
  for (int i = 0; i < 7; i++) {
    h2 o;
    o.x = (f16)ax[i];
    o.y = (f16)ay[i];
    ((h2*)oq)[(size_t)n * 448 + i * 64 + f2] = o;
  }
}

// ---------------- layer 0: aggregate-first (x is only [N,8]), unroll-4 ----------------
__global__ __launch_bounds__(64) void k_agg_x(const float* __restrict__ x,
                                              const f16* __restrict__ csr_norm,
                                              const float* __restrict__ dis,
                                              const int* __restrict__ rowptr,
                                              const int* __restrict__ csr_src,
                                              float* __restrict__ xagg) {
  int n = blockIdx.x;
  int f = threadIdx.x;
  if (f >= 56) return;
  int i = f >> 3, c = f & 7;
  const f16* nrm = csr_norm + (size_t)i * NE;
  float d = dis[i * NN + n];
  float acc = d * d * x[(size_t)n * 8 + c];
  int s = rowptr[n], e = rowptr[n + 1];
  int p = s;
  for (; p + 4 <= e; p += 4) {
    int s0 = csr_src[p], s1 = csr_src[p + 1], s2 = csr_src[p + 2], s3 = csr_src[p + 3];
    float n0 = (float)nrm[p], n1 = (float)nrm[p + 1];
    float n2 = (float)nrm[p + 2], n3 = (float)nrm[p + 3];
    float v0 = x[(size_t)s0 * 8 + c];
    float v1 = x[(size_t)s1 * 8 + c];
    float v2 = x[(size_t)s2 * 8 + c];
    float v3 = x[(size_t)s3 * 8 + c];
    acc = fmaf(n0, v0, acc);
    acc = fmaf(n1, v1, acc);
    acc = fmaf(n2, v2, acc);
    acc = fmaf(n3, v3, acc);
  }
  for (; p < e; p++)
    acc = fmaf((float)nrm[p], x[(size_t)csr_src[p] * 8 + c], acc);
  xagg[(size_t)n * 56 + f] = acc;
}

// x1[n, i*128+h] = relu(b0[i][h] + sum_c xagg[n][i*8+c] * W0[i][c][h]), fp16 out
__global__ __launch_bounds__(896) void k_gemm0(const float* __restrict__ xagg,
                                               const float* __restrict__ W0,
                                               const float* __restrict__ b0,
                                               f16* __restrict__ outq) {
  int n = blockIdx.x;
  int f = threadIdx.x;
  int i = f >> 7, h = f & 127;
  float s = b0[i * 128 + h];
#pragma unroll
  for (int c = 0; c < 8; c++)
    s = fmaf(xagg[(size_t)n * 56 + i * 8 + c], W0[(i * 8 + c) * 128 + h], s);
  outq[(size_t)n * 896 + f] = (f16)fmaxf(s, 0.f);
}

// ---------------- fused link MLP: gather + 3 MFMA layers + output, H in LDS ----
__global__ __launch_bounds__(256) void k_link_fused(
    const f16* __restrict__ UV, const int* __restrict__ eit,
    const float* __restrict__ lb0, const f16* __restrict__ lwht,
    const float* __restrict__ lbh, const float* __restrict__ lw4,
    const float* __restrict__ lb4, float* __restrict__ out) {
  __shared__ f16 Hhi[64 * HP];
  __shared__ f16 Hlo[64 * HP];
  __shared__ f16 Wt[128 * HP];
  __shared__ float ob[64][4];
  const int tid = threadIdx.x;
  const int t0 = blockIdx.x * 32;
  {
    int c = tid & 127;
    int rbase = tid >> 7;  // 0 or 1
    for (int it = 0; it < 32; it++) {
      int rr = rbase + it * 2;
      int tp = t0 + (rr >> 1), dir = rr & 1;
      int s = eit[tp], d = eit[NT + tp];
      int a = dir ? d : s, b = dir ? s : d;
      float v = (float)UV[(size_t)a * 256 + c] + (float)UV[(size_t)b * 256 + 128 + c]
                + lb0[c];
      v = fmaxf(v, 0.f);
      f16 h = (f16)v;
      Hhi[rr * HP + c] = h;
      Hlo[rr * HP + c] = (f16)(v - (float)h);
    }
  }
  const int w = tid >> 6, lane = tid & 63;
  const int quad = lane >> 4, lc = lane & 15;
  for (int l = 0; l < 3; l++) {
    __syncthreads();
    {  // stage W(l): [n][k] fp16 -> padded LDS
      const f16* src = lwht + (size_t)l * 128 * 128;
#pragma unroll
      for (int it = 0; it < 8; it++) {
        int idx = (tid + it * 256) * 8;
        int n = idx >> 7, k = idx & 127;
        *(float4*)&Wt[n * HP + k] = *(const float4*)&src[idx];
      }
    }
    __syncthreads();
    f32x4 acc[8] = {};
    const int arow = w * 16 + lc;
#pragma unroll
    for (int k0 = 0; k0 < 128; k0 += 32) {
      f16x8 ah = *(const f16x8*)&Hhi[arow * HP + k0 + quad * 8];
      f16x8 al = *(const f16x8*)&Hlo[arow * HP + k0 + quad * 8];
#pragma unroll
      for (int nt = 0; nt < 8; nt++) {
        f16x8 bf = *(const f16x8*)&Wt[(nt * 16 + lc) * HP + k0 + quad * 8];
        acc[nt] = __builtin_amdgcn_mfma_f32_16x16x32_f16(ah, bf, acc[nt], 0, 0, 0);
        acc[nt] = __builtin_amdgcn_mfma_f32_16x16x32_f16(al, bf, acc[nt], 0, 0, 0);
      }
    }
#pragma unroll
    for (int nt = 0; nt < 8; nt++) {
      int col = nt * 16 + lc;
      float bb = lbh[l * 128 + col];
#pragma unroll
      for (int r = 0; r < 4; r++) {
        int rrow = w * 16 + quad * 4 + r;
        float v = fmaxf(acc[nt][r] + bb, 0.f);
        f16 h = (f16)v;
        Hhi[rrow * HP + col] = h;
        Hlo[rrow * HP + col] = (f16)(v - (float)h);
      }
    }
  }
  __syncthreads();
  {
    int rr = tid >> 2, j = tid & 3;
    float o = lb4[j];
    for (int k = 0; k < 128; k++) {
      float hv = (float)Hhi[rr * HP + k] + (float)Hlo[rr * HP + k];
      o = fmaf(hv, lw4[k * 4 + j], o);
    }
    ob[rr][j] = o;
  }
  __syncthreads();
  if (tid < 128) {
    int tp = tid >> 2, j = tid & 3;
    const int perm[4] = {0, 2, 1, 3};
    out[(size_t)(t0 + tp) * 4 + j] = 0.5f * (ob[2 * tp][j] + ob[2 * tp + 1][perm[j]]);
  }
}

// ---------------- host ----------------
extern "C" void kernel_launch(void* const* d_in, const int* in_sizes, int n_in,
                              void* d_out, int out_size, void* d_ws, size_t ws_size,
                              hipStream_t stream) {
  const float* x   = (const float*)d_in[0];
  const int*   ei  = (const int*)d_in[1];
  const float* ea  = (const float*)d_in[2];
  const int*   eit = (const int*)d_in[3];
  const float* W0  = (const float*)d_in[4];
  const float* b0  = (const float*)d_in[5];
  const float* W1  = (const float*)d_in[6];
  const float* b1  = (const float*)d_in[7];
  const float* W2  = (const float*)d_in[8];
  const float* b2  = (const float*)d_in[9];
  const float* W3  = (const float*)d_in[10];
  const float* b3  = (const float*)d_in[11];
  const float* ew1 = (const float*)d_in[12];
  const float* eb1 = (const float*)d_in[13];
  const float* ew2 = (const float*)d_in[14];
  const float* eb2 = (const float*)d_in[15];
  const float* ew3 = (const float*)d_in[16];
  const float* eb3 = (const float*)d_in[17];
  const float* lw0 = (const float*)d_in[18];
  const float* lb0 = (const float*)d_in[19];
  const float* lwh = (const float*)d_in[20];
  const float* lbh = (const float*)d_in[21];
  const float* lw4 = (const float*)d_in[22];
  const float* lb4 = (const float*)d_in[23];
  const int* row = ei;
  const int* col = ei + NE;
  float* out = (float*)d_out;

  char* ws = (char*)d_ws;
  size_t off = 0;
  auto alloc = [&](size_t bytes) -> char* {
    char* p = ws + off;
    off += (bytes + 255) & ~(size_t)255;
    return p;
  };
  f16*   xA     = (f16*)alloc((size_t)NN * 896 * 2);  // x1 -> x3 -> x4
  f16*   xB     = (f16*)alloc((size_t)NN * 896 * 2);  // hW1 -> xagg2 -> hW3
  f16*   x2h    = (f16*)alloc((size_t)NN * 128 * 2);
  f16*   UVh    = (f16*)alloc((size_t)NN * 256 * 2);
  float* xagg   = (float*)alloc((size_t)NN * 56 * 4);
  f16*   csr_nrm= (f16*)alloc((size_t)8 * NE * 2);
  float* dis    = (float*)alloc((size_t)8 * NN * 4);
  float* ewb    = (float*)alloc((size_t)NE * 4);
  int*   rowptr = (int*)alloc((size_t)(NN + 1) * 4);
  int*   cursor = (int*)alloc((size_t)NN * 4);
  int*   eid    = (int*)alloc((size_t)NE * 4);
  int*   csr_src= (int*)alloc((size_t)NE * 4);
  f16* w1t  = (f16*)alloc((size_t)128 * 896 * 2);
  f16* w2t  = (f16*)alloc((size_t)7 * 128 * 128 * 2);
  f16* w3t  = (f16*)alloc((size_t)7 * 128 * 896 * 2);
  f16* lw0t = (f16*)alloc((size_t)2 * 128 * 896 * 2);
  f16* lwht = (f16*)alloc((size_t)3 * 128 * 128 * 2);
  (void)ws_size; (void)in_sizes; (void)n_in; (void)out_size;

  const int EB = (NE + 255) / 256;
  const int GX = (NN + 127) / 128;   // 157
  const int MC = (GX + 7) / 8;       // 20 row-tiles max per XCD

  // one-launch weight prep (5 mats) + cursor zero
  k_wprep_all<<<5120 + (NN + 255) / 256, 256, 0, stream>>>(
      W1, W2, W3, lw0, lwh, w1t, w2t, w3t, lw0t, lwht, cursor);

  // edge weight + CSR count (fused) -> scan -> fill -> degrees -> norms (fp16)
  k_edge_mlp<<<EB, 256, 0, stream>>>(ea, ew1, eb1, ew2, eb2, ew3, eb3, col, ewb, cursor);
  k_scan<<<1, 256, 0, stream>>>(cursor, rowptr);
  k_fill_csr<<<EB, 256, 0, stream>>>(col, cursor, eid);
  k_deg_csr<<<(NN + 7) / 8, 64, 0, stream>>>(rowptr, eid, ea, ewb, dis);
  k_csr_norms<<<EB, 256, 0, stream>>>(eid, row, col, ea, ewb, dis, csr_src, csr_nrm);

  // Layer 0 (aggregate-first, split kernels): xagg [N,7,8] -> x1 fp16 (xA)
  k_agg_x<<<NN, 64, 0, stream>>>(x, csr_nrm, dis, rowptr, csr_src, xagg);
  k_gemm0<<<NN, 896, 0, stream>>>(xagg, W0, b0, xA);

  // Layer 1: x1 @ W1 -> hW1 fp16 (xB); agg1 (learned ew, bias+relu) -> x2h fp16
  k_mgemm<1, false, false, false, false><<<dim3(GX, 1), 256, 0, stream>>>(
      xA, w1t, nullptr, nullptr, xB, 896, NN, 896, 1, GX);
  k_agg1<<<(NN + 3) / 4, 256, 0, stream>>>(xB, csr_nrm + (size_t)7 * NE,
                                           dis + (size_t)7 * NN, rowptr, csr_src, b1, x2h);

  // Layer 2 (aggregate-first): xagg2 = A_i * x2 (7 relations, fp16 into xB),
  // then x3 = relu(xagg2_i @ W2_i + b2_i) via GROUP_A GEMM -> xA fp16
  k_agg2<<<(NN + 3) / 4, 256, 0, stream>>>(x2h, csr_nrm, dis, rowptr, csr_src, xB);
  k_mgemm<1, true, true, true, false><<<dim3(GX, 7), 256, 0, stream>>>(
      xB, w2t, b2, nullptr, xA, 896, NN, 128, 7, GX);

  // Layer 3: x3 @ W3 (7 mats, K=896, XCD-swizzled) -> hW3 fp16 (xB);
  // agg7 (R11 node-per-block) -> x4 (xA)
  k_mgemm<1, false, false, false, true><<<dim3(8 * MC * 7), 256, 0, stream>>>(
      xA, w3t, nullptr, nullptr, xB, 896, NN, 896, 7, GX);
  k_agg7<<<NN, 448, 0, stream>>>(xB, csr_nrm, dis, rowptr, csr_src, b3, xA);

  // Link precompute: UV = x4 @ [lw0_top | lw0_bot]  (XCD-swizzled, NG=2, fp16 out)
  k_mgemm<1, false, false, false, true><<<dim3(8 * MC * 2), 256, 0, stream>>>(
      xA, lw0t, nullptr, nullptr, UVh, 896, NN, 896, 2, GX);

  // Fused link MLP: gather + 3 layers + output dot, H resident in LDS
  k_link_fused<<<NT / 32, 256, 0, stream>>>(UVh, eit, lb0, lwht, lbh, lw4, lb4, out);
}

// Round 16
// 566.763 us; speedup vs baseline: 1.0277x; 1.0277x over previous
//
#include <hip/hip_runtime.h>
#include <math.h>

#define NN 20000
#define NE 200000
#define NT 40000
#define HP 136  // padded LDS row stride (fp16) for link H/W tiles

typedef _Float16 f16;
typedef __attribute__((ext_vector_type(8))) _Float16 f16x8;
typedef __attribute__((ext_vector_type(4))) float f32x4;
typedef __attribute__((ext_vector_type(2))) _Float16 h2;

// ---------------- edge weight MLP (+ CSR count fused) ----------------
__global__ void k_edge_mlp(const float* __restrict__ ea,
                           const float* __restrict__ w1, const float* __restrict__ b1,
                           const float* __restrict__ w2, const float* __restrict__ b2,
                           const float* __restrict__ w3, const float* __restrict__ b3,
                           const int* __restrict__ col,
                           float* __restrict__ out, int* __restrict__ cnt) {
  int e = blockIdx.x * 256 + threadIdx.x;
  if (e >= NE) return;
  atomicAdd(&cnt[col[e]], 1);
  float a[7];
#pragma unroll
  for (int i = 0; i < 7; i++) a[i] = ea[e * 7 + i];
  float t1[28];
#pragma unroll
  for (int j = 0; j < 28; j++) {
    float s = b1[j];
#pragma unroll
    for (int k = 0; k < 7; k++) s = fmaf(a[k], w1[k * 28 + j], s);
    t1[j] = fmaxf(s, 0.f);
  }
  float t2[28];
  for (int j = 0; j < 28; j++) {
    float s = b2[j];
    for (int k = 0; k < 28; k++) s = fmaf(t1[k], w2[k * 28 + j], s);
    t2[j] = fmaxf(s, 0.f);
  }
  float s = b3[0];
  for (int k = 0; k < 28; k++) s = fmaf(t2[k], w3[k], s);
  out[e] = 1.f / (1.f + expf(-s));
}

// ---------------- CSR scan: rowptr + cursor in one pass ----------------
__global__ void k_scan(int* __restrict__ cnt, int* __restrict__ rowptr) {
  __shared__ int sums[256];
  __shared__ int offs[256];
  int t = threadIdx.x;
  const int CH = (NN + 255) / 256;
  int base = t * CH;
  int s = 0;
  for (int i = 0; i < CH; i++) { int idx = base + i; if (idx < NN) s += cnt[idx]; }
  sums[t] = s;
  __syncthreads();
  if (t == 0) {
    int acc = 0;
    for (int i = 0; i < 256; i++) { offs[i] = acc; acc += sums[i]; }
    rowptr[NN] = acc;
  }
  __syncthreads();
  int acc = offs[t];
  for (int i = 0; i < CH; i++) {
    int idx = base + i;
    if (idx < NN) {
      int cv = cnt[idx];
      rowptr[idx] = acc;
      cnt[idx] = acc;  // becomes the fill cursor
      acc += cv;
    }
  }
}

__global__ void k_fill_csr(const int* __restrict__ col, int* __restrict__ cursor,
                           int* __restrict__ eid) {
  int e = blockIdx.x * 256 + threadIdx.x;
  if (e >= NE) return;
  int pos = atomicAdd(&cursor[col[e]], 1);
  eid[pos] = e;
}

// degrees from CSR (no float atomics). 8 nodes x 8 relations per 64-thread block.
__global__ __launch_bounds__(64) void k_deg_csr(const int* __restrict__ rowptr,
                                                const int* __restrict__ eid,
                                                const float* __restrict__ ea,
                                                const float* __restrict__ ewb,
                                                float* __restrict__ dis) {
  int t = threadIdx.x;
  int n = blockIdx.x * 8 + (t >> 3);
  int i = t & 7;
  if (n >= NN) return;
  float deg = 1.f;  // self-loop weight
  int s = rowptr[n], e2 = rowptr[n + 1];
  for (int p = s; p < e2; p++) {
    int e = eid[p];
    deg += (i < 7) ? ea[e * 7 + i] : ewb[e];
  }
  dis[i * NN + n] = rsqrtf(deg);  // deg >= 1 always
}

__global__ void k_csr_norms(const int* __restrict__ eid, const int* __restrict__ row,
                            const int* __restrict__ col, const float* __restrict__ ea,
                            const float* __restrict__ ew, const float* __restrict__ dis,
                            int* __restrict__ csr_src, float* __restrict__ csr_norm) {
  int p = blockIdx.x * 256 + threadIdx.x;
  if (p >= NE) return;
  int e = eid[p];
  int r = row[e], c = col[e];
  csr_src[p] = r;
#pragma unroll
  for (int i = 0; i < 7; i++)
    csr_norm[i * NE + p] = dis[i * NN + r] * ea[e * 7 + i] * dis[i * NN + c];
  csr_norm[7 * NE + p] = dis[7 * NN + r] * ew[e] * dis[7 * NN + c];
}

// ---------------- single-launch weight prep (all 5 mats) + cursor zero ----------------
__global__ void k_wprep_all(const float* __restrict__ W1, const float* __restrict__ W2,
                            const float* __restrict__ W3, const float* __restrict__ lw0,
                            const float* __restrict__ lwh,
                            f16* __restrict__ w1t, f16* __restrict__ w2t,
                            f16* __restrict__ w3t, f16* __restrict__ lw0t,
                            f16* __restrict__ lwht, int* __restrict__ cursor) {
  int b = blockIdx.x, t = threadIdx.x;
  const float* W;
  f16* D;
  int K, g, tile;
  size_t matOff;
  if (b < 448) {            // W1: K=896, 1 mat
    W = W1; D = w1t; K = 896; g = 0; tile = b; matOff = 0;
  } else if (b < 896) {     // W2: K=128, 7 mats
    int l = b - 448; W = W2; D = w2t; K = 128; g = l >> 6; tile = l & 63;
    matOff = 16384;
  } else if (b < 4032) {    // W3: K=896, 7 mats
    int l = b - 896; W = W3; D = w3t; K = 896; g = l / 448; tile = l % 448;
    matOff = 114688;
  } else if (b < 4928) {    // lw0: K=896, 2 mats (U rows 0..895, V rows 896..1791)
    int l = b - 4032; W = lw0; D = lw0t; K = 896; g = l / 448; tile = l % 448;
    matOff = 114688;
  } else if (b < 5120) {    // lwh: K=128, 3 mats
    int l = b - 4928; W = lwh; D = lwht; K = 128; g = l >> 6; tile = l & 63;
    matOff = 16384;
  } else {                  // zero the CSR cursor
    int idx = (b - 5120) * 256 + t;
    if (idx < NN) cursor[idx] = 0;
    return;
  }
  int idx = tile * 256 + t;
  int k = idx >> 7, n = idx & 127;
  float v = W[(size_t)g * matOff + (size_t)k * 128 + n];
  D[(size_t)g * 128 * K + (size_t)n * K + k] = (f16)v;
}

// ---------------- fp16 MFMA GEMM (1-term) ----------------
template <int OUTM, bool RELU, bool BIAS, bool GROUP_A, bool SWIZZLE>
__global__ __launch_bounds__(256) void k_mgemm(
    const f16* __restrict__ A, const f16* __restrict__ BT,
    const float* __restrict__ bias,
    float* __restrict__ Cf, f16* __restrict__ Ch,
    int ldA, int M, int K, int NG, int GXp) {
  int rowT, g;
  if (SWIZZLE) {
    int b = blockIdx.x;
    int xcd = b & 7, s = b >> 3;
    g = s % NG;
    int lr = s / NG;
    rowT = lr * 8 + xcd;
    if (rowT >= GXp) return;  // uniform early-out (padded grid)
  } else {
    rowT = blockIdx.x;
    g = blockIdx.y;
  }
  __shared__ f16 smem[8192];  // 2 tiles [128 rows][32 k] fp16: A, B
  const int tid = threadIdx.x;
  const int w = tid >> 6, lane = tid & 63;
  const int quad = lane >> 4, lc = lane & 15;
  const int wr = w >> 1, wc = w & 1;
  const int bm = rowT * 128;
  const int ldC = NG * 128;
  const int cb = g * 128;
  const int aoff = GROUP_A ? g * K : 0;
  const f16* Bg = BT + (size_t)g * 128 * K;
  const int srow = lane >> 2, skoff = (lane & 3) * 8;

  f32x4 acc[4][4] = {};

  for (int k0 = 0; k0 < K; k0 += 32) {
#pragma unroll
    for (int l = 0; l < 4; l++) {
      int c = w + l * 4;
      int t = c >> 3, r16 = c & 7;
      int rowi = r16 * 16 + srow;
      f16* ldst = smem + t * 4096 + r16 * 512;  // +lane*16B implicit
      const f16* src;
      if (t == 0) {
        int gm = bm + rowi;
        if (gm > M - 1) gm = M - 1;  // clamp; guarded at store
        src = A + (size_t)gm * ldA + aoff + k0 + skoff;
      } else {
        src = Bg + (size_t)rowi * K + k0 + skoff;
      }
      __builtin_amdgcn_global_load_lds(
          (const __attribute__((address_space(1))) void*)src,
          (__attribute__((address_space(3))) void*)ldst, 16, 0, 0);
    }
    __syncthreads();
    f16x8 bf[4];
#pragma unroll
    for (int nt = 0; nt < 4; nt++) {
      int r = wc * 64 + nt * 16 + lc;
      bf[nt] = *(const f16x8*)(smem + 4096 + r * 32 + quad * 8);
    }
#pragma unroll
    for (int mt = 0; mt < 4; mt++) {
      int r = wr * 64 + mt * 16 + lc;
      f16x8 ah = *(const f16x8*)(smem + r * 32 + quad * 8);
#pragma unroll
      for (int nt = 0; nt < 4; nt++) {
        acc[mt][nt] = __builtin_amdgcn_mfma_f32_16x16x32_f16(ah, bf[nt], acc[mt][nt], 0, 0, 0);
      }
    }
    __syncthreads();
  }

  float bv[4];
  if (BIAS) {
#pragma unroll
    for (int nt = 0; nt < 4; nt++) bv[nt] = bias[cb + wc * 64 + nt * 16 + lc];
  }
#pragma unroll
  for (int mt = 0; mt < 4; mt++) {
#pragma unroll
    for (int r = 0; r < 4; r++) {
      int gm = bm + wr * 64 + mt * 16 + quad * 4 + r;
      if (gm >= M) continue;
#pragma unroll
      for (int nt = 0; nt < 4; nt++) {
        float v = acc[mt][nt][r];
        if (BIAS) v += bv[nt];
        if (RELU) v = fmaxf(v, 0.f);
        size_t idx = (size_t)gm * ldC + cb + wc * 64 + nt * 16 + lc;
        if (OUTM == 1) Ch[idx] = (f16)v;
        else Cf[idx] = v;
      }
    }
  }
}

// ---------------- layer-3 aggregation: R11-proven node-per-block, unroll-8 ----
// Full-random gather at ~3.6 TB/s (measured floor — beats relation-sliced L2
// variants R12/R13 and fp16-norm variant R15).
__global__ __launch_bounds__(448) void k_agg7(const f16* __restrict__ hW,
                                              const float* __restrict__ csr_norm,
                                              const float* __restrict__ dis,
                                              const int* __restrict__ rowptr,
                                              const int* __restrict__ csr_src,
                                              const float* __restrict__ bias,
                                              f16* __restrict__ outq) {
  int n = blockIdx.x;
  int f2 = threadIdx.x;   // handles h2 col f2 (cols 2*f2, 2*f2+1)
  int i = f2 >> 6;        // wave-uniform relation
  const h2* hw2 = (const h2*)hW;
  const float* nrm = csr_norm + (size_t)i * NE;
  float d = dis[i * NN + n];
  h2 sv = hw2[(size_t)n * 448 + f2];
  float ax = d * d * (float)sv.x, ay = d * d * (float)sv.y;
  int s = rowptr[n], e = rowptr[n + 1];
  int p = s;
  for (; p + 8 <= e; p += 8) {
    int si[8];
    float nn_[8];
    h2 vv[8];
#pragma unroll
    for (int u = 0; u < 8; u++) { si[u] = csr_src[p + u]; nn_[u] = nrm[p + u]; }
#pragma unroll
    for (int u = 0; u < 8; u++) vv[u] = hw2[(size_t)si[u] * 448 + f2];
#pragma unroll
    for (int u = 0; u < 8; u++) {
      ax = fmaf(nn_[u], (float)vv[u].x, ax);
      ay = fmaf(nn_[u], (float)vv[u].y, ay);
    }
  }
  for (; p + 4 <= e; p += 4) {
    int s0 = csr_src[p], s1 = csr_src[p + 1], s2 = csr_src[p + 2], s3 = csr_src[p + 3];
    float n0 = nrm[p], n1 = nrm[p + 1], n2 = nrm[p + 2], n3 = nrm[p + 3];
    h2 v0 = hw2[(size_t)s0 * 448 + f2];
    h2 v1 = hw2[(size_t)s1 * 448 + f2];
    h2 v2 = hw2[(size_t)s2 * 448 + f2];
    h2 v3 = hw2[(size_t)s3 * 448 + f2];
    ax = fmaf(n0, (float)v0.x, ax); ay = fmaf(n0, (float)v0.y, ay);
    ax = fmaf(n1, (float)v1.x, ax); ay = fmaf(n1, (float)v1.y, ay);
    ax = fmaf(n2, (float)v2.x, ax); ay = fmaf(n2, (float)v2.y, ay);
    ax = fmaf(n3, (float)v3.x, ax); ay = fmaf(n3, (float)v3.y, ay);
  }
  for (; p < e; p++) {
    int s0 = csr_src[p];
    float n0 = nrm[p];
    h2 v0 = hw2[(size_t)s0 * 448 + f2];
    ax = fmaf(n0, (float)v0.x, ax); ay = fmaf(n0, (float)v0.y, ay);
  }
  h2 o;
  o.x = (f16)fmaxf(ax + bias[2 * f2], 0.f);
  o.y = (f16)fmaxf(ay + bias[2 * f2 + 1], 0.f);
  ((h2*)outq)[(size_t)n * 448 + f2] = o;
}

// ---------------- layer-1 aggregation: fp16 gather, fp16 out, unroll-8 ----------------
__global__ __launch_bounds__(256) void k_agg1(const f16* __restrict__ hW,
                                              const float* __restrict__ nrm,
                                              const float* __restrict__ dis_i,
                                              const int* __restrict__ rowptr,
                                              const int* __restrict__ csr_src,
                                              const float* __restrict__ bias,
                                              f16* __restrict__ x2h) {
  int t = threadIdx.x;
  int n = blockIdx.x * 4 + (t >> 6);
  int f2 = t & 63;
  if (n >= NN) return;
  const h2* hw2 = (const h2*)hW;
  float d = dis_i[n];
  h2 sv = hw2[(size_t)n * 64 + f2];
  float ax = d * d * (float)sv.x, ay = d * d * (float)sv.y;
  int s = rowptr[n], e = rowptr[n + 1];
  int p = s;
  for (; p + 8 <= e; p += 8) {
    int si[8];
    float nn_[8];
    h2 vv[8];
#pragma unroll
    for (int u = 0; u < 8; u++) { si[u] = csr_src[p + u]; nn_[u] = nrm[p + u]; }
#pragma unroll
    for (int u = 0; u < 8; u++) vv[u] = hw2[(size_t)si[u] * 64 + f2];
#pragma unroll
    for (int u = 0; u < 8; u++) {
      ax = fmaf(nn_[u], (float)vv[u].x, ax);
      ay = fmaf(nn_[u], (float)vv[u].y, ay);
    }
  }
  for (; p < e; p++) {
    int s0 = csr_src[p];
    float n0 = nrm[p];
    h2 v0 = hw2[(size_t)s0 * 64 + f2];
    ax = fmaf(n0, (float)v0.x, ax); ay = fmaf(n0, (float)v0.y, ay);
  }
  h2 o;
  o.x = (f16)fmaxf(ax + bias[2 * f2], 0.f);
  o.y = (f16)fmaxf(ay + bias[2 * f2 + 1], 0.f);
  ((h2*)x2h)[(size_t)n * 64 + f2] = o;
}

// ---------------- layer-2 aggregate-first: fp16 gather of x2, 7 norms, unroll-4 ----
__global__ __launch_bounds__(256) void k_agg2(const f16* __restrict__ x2h,
                                              const float* __restrict__ csr_norm,
                                              const float* __restrict__ dis,
                                              const int* __restrict__ rowptr,
                                              const int* __restrict__ csr_src,
                                              f16* __restrict__ oq) {
  int t = threadIdx.x;
  int n = blockIdx.x * 4 + (t >> 6);
  int f2 = t & 63;
  if (n >= NN) return;
  const h2* x2 = (const h2*)x2h;
  h2 svh = x2[(size_t)n * 64 + f2];
  float svx = (float)svh.x, svy = (float)svh.y;
  float ax[7], ay[7];
#pragma unroll
  for (int i = 0; i < 7; i++) {
    float d = dis[i * NN + n];
    ax[i] = d * d * svx;
    ay[i] = d * d * svy;
  }
  int s = rowptr[n], e = rowptr[n + 1];
  int p = s;
  for (; p + 4 <= e; p += 4) {
    int si[4];
    h2 vv[4];
#pragma unroll
    for (int u = 0; u < 4; u++) si[u] = csr_src[p + u];
#pragma unroll
    for (int u = 0; u < 4; u++) vv[u] = x2[(size_t)si[u] * 64 + f2];
#pragma unroll
    for (int i = 0; i < 7; i++) {
#pragma unroll
      for (int u = 0; u < 4; u++) {
        float nw = csr_norm[(size_t)i * NE + p + u];
        ax[i] = fmaf(nw, (float)vv[u].x, ax[i]);
        ay[i] = fmaf(nw, (float)vv[u].y, ay[i]);
      }
    }
  }
  for (; p < e; p++) {
    int s0 = csr_src[p];
    h2 v0 = x2[(size_t)s0 * 64 + f2];
#pragma unroll
    for (int i = 0; i < 7; i++) {
      float nw = csr_norm[(size_t)i * NE + p];
      ax[i] = fmaf(nw, (float)v0.x, ax[i]);
      ay[i] = fmaf(nw, (float)v0.y, ay[i]);
    }
  }
#pragma unroll
  for (int i = 0; i < 7; i++) {
    h2 o;
    o.x = (f16)ax[i];
    o.y = (f16)ay[i];
    ((h2*)oq)[(size_t)n * 448 + i * 64 + f2] = o;
  }
}

// ---------------- layer 0: aggregate-first (x is only [N,8]), unroll-4 ----------------
__global__ __launch_bounds__(64) void k_agg_x(const float* __restrict__ x,
                                              const float* __restrict__ csr_norm,
                                              const float* __restrict__ dis,
                                              const int* __restrict__ rowptr,
                                              const int* __restrict__ csr_src,
                                              float* __restrict__ xagg) {
  int n = blockIdx.x;
  int f = threadIdx.x;
  if (f >= 56) return;
  int i = f >> 3, c = f & 7;
  const float* nrm = csr_norm + (size_t)i * NE;
  float d = dis[i * NN + n];
  float acc = d * d * x[(size_t)n * 8 + c];
  int s = rowptr[n], e = rowptr[n + 1];
  int p = s;
  for (; p + 4 <= e; p += 4) {
    int s0 = csr_src[p], s1 = csr_src[p + 1], s2 = csr_src[p + 2], s3 = csr_src[p + 3];
    float n0 = nrm[p], n1 = nrm[p + 1], n2 = nrm[p + 2], n3 = nrm[p + 3];
    float v0 = x[(size_t)s0 * 8 + c];
    float v1 = x[(size_t)s1 * 8 + c];
    float v2 = x[(size_t)s2 * 8 + c];
    float v3 = x[(size_t)s3 * 8 + c];
    acc = fmaf(n0, v0, acc);
    acc = fmaf(n1, v1, acc);
    acc = fmaf(n2, v2, acc);
    acc = fmaf(n3, v3, acc);
  }
  for (; p < e; p++)
    acc = fmaf(nrm[p], x[(size_t)csr_src[p] * 8 + c], acc);
  xagg[(size_t)n * 56 + f] = acc;
}

// x1[n, i*128+h] = relu(b0[i][h] + sum_c xagg[n][i*8+c] * W0[i][c][h]), fp16 out
__global__ __launch_bounds__(896) void k_gemm0(const float* __restrict__ xagg,
                                               const float* __restrict__ W0,
                                               const float* __restrict__ b0,
                                               f16* __restrict__ outq) {
  int n = blockIdx.x;
  int f = threadIdx.x;
  int i = f >> 7, h = f & 127;
  float s = b0[i * 128 + h];
#pragma unroll
  for (int c = 0; c < 8; c++)
    s = fmaf(xagg[(size_t)n * 56 + i * 8 + c], W0[(i * 8 + c) * 128 + h], s);
  outq[(size_t)n * 896 + f] = (f16)fmaxf(s, 0.f);
}

// ---------------- fused link MLP: gather + 3 MFMA layers + output, H in LDS ----
__global__ __launch_bounds__(256) void k_link_fused(
    const f16* __restrict__ UV, const int* __restrict__ eit,
    const float* __restrict__ lb0, const f16* __restrict__ lwht,
    const float* __restrict__ lbh, const float* __restrict__ lw4,
    const float* __restrict__ lb4, float* __restrict__ out) {
  __shared__ f16 Hhi[64 * HP];
  __shared__ f16 Hlo[64 * HP];
  __shared__ f16 Wt[128 * HP];
  __shared__ float ob[64][4];
  const int tid = threadIdx.x;
  const int t0 = blockIdx.x * 32;
  {
    int c = tid & 127;
    int rbase = tid >> 7;  // 0 or 1
    for (int it = 0; it < 32; it++) {
      int rr = rbase + it * 2;
      int tp = t0 + (rr >> 1), dir = rr & 1;
      int s = eit[tp], d = eit[NT + tp];
      int a = dir ? d : s, b = dir ? s : d;
      float v = (float)UV[(size_t)a * 256 + c] + (float)UV[(size_t)b * 256 + 128 + c]
                + lb0[c];
      v = fmaxf(v, 0.f);
      f16 h = (f16)v;
      Hhi[rr * HP + c] = h;
      Hlo[rr * HP + c] = (f16)(v - (float)h);
    }
  }
  const int w = tid >> 6, lane = tid & 63;
  const int quad = lane >> 4, lc = lane & 15;
  for (int l = 0; l < 3; l++) {
    __syncthreads();
    {  // stage W(l): [n][k] fp16 -> padded LDS
      const f16* src = lwht + (size_t)l * 128 * 128;
#pragma unroll
      for (int it = 0; it < 8; it++) {
        int idx = (tid + it * 256) * 8;
        int n = idx >> 7, k = idx & 127;
        *(float4*)&Wt[n * HP + k] = *(const float4*)&src[idx];
      }
    }
    __syncthreads();
    f32x4 acc[8] = {};
    const int arow = w * 16 + lc;
#pragma unroll
    for (int k0 = 0; k0 < 128; k0 += 32) {
      f16x8 ah = *(const f16x8*)&Hhi[arow * HP + k0 + quad * 8];
      f16x8 al = *(const f16x8*)&Hlo[arow * HP + k0 + quad * 8];
#pragma unroll
      for (int nt = 0; nt < 8; nt++) {
        f16x8 bf = *(const f16x8*)&Wt[(nt * 16 + lc) * HP + k0 + quad * 8];
        acc[nt] = __builtin_amdgcn_mfma_f32_16x16x32_f16(ah, bf, acc[nt], 0, 0, 0);
        acc[nt] = __builtin_amdgcn_mfma_f32_16x16x32_f16(al, bf, acc[nt], 0, 0, 0);
      }
    }
#pragma unroll
    for (int nt = 0; nt < 8; nt++) {
      int col = nt * 16 + lc;
      float bb = lbh[l * 128 + col];
#pragma unroll
      for (int r = 0; r < 4; r++) {
        int rrow = w * 16 + quad * 4 + r;
        float v = fmaxf(acc[nt][r] + bb, 0.f);
        f16 h = (f16)v;
        Hhi[rrow * HP + col] = h;
        Hlo[rrow * HP + col] = (f16)(v - (float)h);
      }
    }
  }
  __syncthreads();
  {
    int rr = tid >> 2, j = tid & 3;
    float o = lb4[j];
    for (int k = 0; k < 128; k++) {
      float hv = (float)Hhi[rr * HP + k] + (float)Hlo[rr * HP + k];
      o = fmaf(hv, lw4[k * 4 + j], o);
    }
    ob[rr][j] = o;
  }
  __syncthreads();
  if (tid < 128) {
    int tp = tid >> 2, j = tid & 3;
    const int perm[4] = {0, 2, 1, 3};
    out[(size_t)(t0 + tp) * 4 + j] = 0.5f * (ob[2 * tp][j] + ob[2 * tp + 1][perm[j]]);
  }
}

// ---------------- host ----------------
extern "C" void kernel_launch(void* const* d_in, const int* in_sizes, int n_in,
                              void* d_out, int out_size, void* d_ws, size_t ws_size,
                              hipStream_t stream) {
  const float* x   = (const float*)d_in[0];
  const int*   ei  = (const int*)d_in[1];
  const float* ea  = (const float*)d_in[2];
  const int*   eit = (const int*)d_in[3];
  const float* W0  = (const float*)d_in[4];
  const float* b0  = (const float*)d_in[5];
  const float* W1  = (const float*)d_in[6];
  const float* b1  = (const float*)d_in[7];
  const float* W2  = (const float*)d_in[8];
  const float* b2  = (const float*)d_in[9];
  const float* W3  = (const float*)d_in[10];
  const float* b3  = (const float*)d_in[11];
  const float* ew1 = (const float*)d_in[12];
  const float* eb1 = (const float*)d_in[13];
  const float* ew2 = (const float*)d_in[14];
  const float* eb2 = (const float*)d_in[15];
  const float* ew3 = (const float*)d_in[16];
  const float* eb3 = (const float*)d_in[17];
  const float* lw0 = (const float*)d_in[18];
  const float* lb0 = (const float*)d_in[19];
  const float* lwh = (const float*)d_in[20];
  const float* lbh = (const float*)d_in[21];
  const float* lw4 = (const float*)d_in[22];
  const float* lb4 = (const float*)d_in[23];
  const int* row = ei;
  const int* col = ei + NE;
  float* out = (float*)d_out;

  char* ws = (char*)d_ws;
  size_t off = 0;
  auto alloc = [&](size_t bytes) -> char* {
    char* p = ws + off;
    off += (bytes + 255) & ~(size_t)255;
    return p;
  };
  f16*   xA     = (f16*)alloc((size_t)NN * 896 * 2);  // x1 -> x3 -> x4
  f16*   xB     = (f16*)alloc((size_t)NN * 896 * 2);  // hW1 -> xagg2 -> hW3
  f16*   x2h    = (f16*)alloc((size_t)NN * 128 * 2);
  f16*   UVh    = (f16*)alloc((size_t)NN * 256 * 2);
  float* xagg   = (float*)alloc((size_t)NN * 56 * 4);
  float* csr_nrm= (float*)alloc((size_t)8 * NE * 4);
  float* dis    = (float*)alloc((size_t)8 * NN * 4);
  float* ewb    = (float*)alloc((size_t)NE * 4);
  int*   rowptr = (int*)alloc((size_t)(NN + 1) * 4);
  int*   cursor = (int*)alloc((size_t)NN * 4);
  int*   eid    = (int*)alloc((size_t)NE * 4);
  int*   csr_src= (int*)alloc((size_t)NE * 4);
  f16* w1t  = (f16*)alloc((size_t)128 * 896 * 2);
  f16* w2t  = (f16*)alloc((size_t)7 * 128 * 128 * 2);
  f16* w3t  = (f16*)alloc((size_t)7 * 128 * 896 * 2);
  f16* lw0t = (f16*)alloc((size_t)2 * 128 * 896 * 2);
  f16* lwht = (f16*)alloc((size_t)3 * 128 * 128 * 2);
  (void)ws_size; (void)in_sizes; (void)n_in; (void)out_size;

  const int EB = (NE + 255) / 256;
  const int GX = (NN + 127) / 128;   // 157
  const int MC = (GX + 7) / 8;       // 20 row-tiles max per XCD

  // one-launch weight prep (5 mats) + cursor zero
  k_wprep_all<<<5120 + (NN + 255) / 256, 256, 0, stream>>>(
      W1, W2, W3, lw0, lwh, w1t, w2t, w3t, lw0t, lwht, cursor);

  // edge weight + CSR count (fused) -> scan -> fill -> degrees -> norms
  k_edge_mlp<<<EB, 256, 0, stream>>>(ea, ew1, eb1, ew2, eb2, ew3, eb3, col, ewb, cursor);
  k_scan<<<1, 256, 0, stream>>>(cursor, rowptr);
  k_fill_csr<<<EB, 256, 0, stream>>>(col, cursor, eid);
  k_deg_csr<<<(NN + 7) / 8, 64, 0, stream>>>(rowptr, eid, ea, ewb, dis);
  k_csr_norms<<<EB, 256, 0, stream>>>(eid, row, col, ea, ewb, dis, csr_src, csr_nrm);

  // Layer 0 (aggregate-first, split kernels): xagg [N,7,8] -> x1 fp16 (xA)
  k_agg_x<<<NN, 64, 0, stream>>>(x, csr_nrm, dis, rowptr, csr_src, xagg);
  k_gemm0<<<NN, 896, 0, stream>>>(xagg, W0, b0, xA);

  // Layer 1: x1 @ W1 -> hW1 fp16 (xB); agg1 (learned ew, bias+relu) -> x2h fp16
  k_mgemm<1, false, false, false, false><<<dim3(GX, 1), 256, 0, stream>>>(
      xA, w1t, nullptr, nullptr, xB, 896, NN, 896, 1, GX);
  k_agg1<<<(NN + 3) / 4, 256, 0, stream>>>(xB, csr_nrm + (size_t)7 * NE,
                                           dis + (size_t)7 * NN, rowptr, csr_src, b1, x2h);

  // Layer 2 (aggregate-first): xagg2 = A_i * x2 (7 relations, fp16 into xB),
  // then x3 = relu(xagg2_i @ W2_i + b2_i) via GROUP_A GEMM -> xA fp16
  k_agg2<<<(NN + 3) / 4, 256, 0, stream>>>(x2h, csr_nrm, dis, rowptr, csr_src, xB);
  k_mgemm<1, true, true, true, false><<<dim3(GX, 7), 256, 0, stream>>>(
      xB, w2t, b2, nullptr, xA, 896, NN, 128, 7, GX);

  // Layer 3: x3 @ W3 (7 mats, K=896, XCD-swizzled) -> hW3 fp16 (xB);
  // agg7 (R11 node-per-block) -> x4 (xA)
  k_mgemm<1, false, false, false, true><<<dim3(8 * MC * 7), 256, 0, stream>>>(
      xA, w3t, nullptr, nullptr, xB, 896, NN, 896, 7, GX);
  k_agg7<<<NN, 448, 0, stream>>>(xB, csr_nrm, dis, rowptr, csr_src, b3, xA);

  // Link precompute: UV = x4 @ [lw0_top | lw0_bot]  (XCD-swizzled, NG=2, fp16 out)
  k_mgemm<1, false, false, false, true><<<dim3(8 * MC * 2), 256, 0, stream>>>(
      xA, lw0t, nullptr, nullptr, UVh, 896, NN, 896, 2, GX);

  // Fused link MLP: gather + 3 layers + output dot, H resident in LDS
  k_link_fused<<<NT / 32, 256, 0, stream>>>(UVh, eit, lb0, lwht, lbh, lw4, lb4, out);
}